// Round 1
// baseline (158.249 us; speedup 1.0000x reference)
//
#include <hip/hip_runtime.h>

// KLD RepPoints loss: per-element 2x2 Gaussian KL + scalar mean reduction.
// Memory-bound streaming kernel: 104 MB in, 4 B out. float2 loads (72 B/elem
// pred stride is 8-aligned, not 16), wave shuffle + LDS + atomicAdd reduce.

__global__ __launch_bounds__(256) void kld_reppoints_kernel(
    const float* __restrict__ pred,    // [n][9][2]
    const float* __restrict__ target,  // [n][4][2]
    float* __restrict__ out,           // [1]
    int n_total, float inv_n)
{
    int n = blockIdx.x * blockDim.x + threadIdx.x;
    float loss = 0.0f;
    if (n < n_total) {
        // ---- pred moments ----
        const float2* p = reinterpret_cast<const float2*>(pred + (size_t)n * 18);
        float px[9], py[9];
        float sx = 0.f, sy = 0.f;
        #pragma unroll
        for (int k = 0; k < 9; ++k) {
            float2 v = p[k];
            px[k] = v.x; py[k] = v.y;
            sx += v.x; sy += v.y;
        }
        const float inv9 = 1.0f / 9.0f;
        float mux = sx * inv9, muy = sy * inv9;
        float a = 0.f, b = 0.f, d = 0.f;   // p_var = [[a,b],[b,d]]
        #pragma unroll
        for (int k = 0; k < 9; ++k) {
            float xx = px[k] - mux, yy = py[k] - muy;
            a += xx * xx; b += xx * yy; d += yy * yy;
        }
        a = a * inv9 + 1e-6f;
        b = b * inv9;
        d = d * inv9 + 1e-6f;

        // ---- target box -> rotated Gaussian ----
        const float2* t = reinterpret_cast<const float2*>(target + (size_t)n * 8);
        float2 t0 = t[0], t1 = t[1], t2 = t[2], t3 = t[3];
        float tmux = (t0.x + t1.x + t2.x + t3.x) * 0.25f;
        float tmuy = (t0.y + t1.y + t2.y + t3.y) * 0.25f;
        float e1x = t1.x - t0.x, e1y = t1.y - t0.y;
        float e2x = t2.x - t1.x, e2y = t2.y - t1.y;
        float w = e1x * e1x + e1y * e1y;
        float h = e2x * e2x + e2y * e2y;
        float sw = sqrtf(w);
        float c = e1x / sw, s = e1y / sw;
        const float invLL = 1.0f / 36.0f;      // 1/(4*L*L), L=3
        float dw = w * invLL, dh = h * invLL;
        // t_var = R diag(dw,dh) R^T
        float tv00 = c * c * dw + s * s * dh;
        float tv01 = c * s * (dw - dh);
        float tv11 = s * s * dw + c * c * dh;

        float t_det = tv00 * tv11 - tv01 * tv01;
        float p_det = a * d - b * b;
        float inv_tdet = 1.0f / t_det;

        float dx = mux - tmux, dy = muy - tmuy;
        // term1 = delta^T t_inv delta ; t_inv = adj(t_var)/t_det
        float term1 = (dx * dx * tv11 - 2.0f * dx * dy * tv01 + dy * dy * tv00) * inv_tdet;
        // trace(t_inv * p_var)
        float trace = (tv11 * a - 2.0f * tv01 * b + tv00 * d) * inv_tdet;
        float term2 = trace + logf(t_det / p_det);
        float kld = 0.5f * (term1 + term2) - 1.0f;
        float kl = fmaxf(kld, 1e-6f);
        loss = 1.0f - 1.0f / (2.0f + sqrtf(kl));
    }

    // ---- reduction: wave64 shuffle -> LDS -> one atomic per block ----
    #pragma unroll
    for (int off = 32; off > 0; off >>= 1)
        loss += __shfl_down(loss, off, 64);

    __shared__ float sm[4];                 // 256 threads / 64 lanes
    int lane = threadIdx.x & 63;
    int wid  = threadIdx.x >> 6;
    if (lane == 0) sm[wid] = loss;
    __syncthreads();
    if (threadIdx.x == 0) {
        float tot = sm[0] + sm[1] + sm[2] + sm[3];
        atomicAdd(out, tot * inv_n);
    }
}

extern "C" void kernel_launch(void* const* d_in, const int* in_sizes, int n_in,
                              void* d_out, int out_size, void* d_ws, size_t ws_size,
                              hipStream_t stream) {
    const float* pred   = (const float*)d_in[0];
    const float* target = (const float*)d_in[1];
    float* out = (float*)d_out;

    int n = in_sizes[0] / 18;   // N elements (pred is N*9*2 floats)

    // harness poisons d_out with 0xAA before every timed launch
    hipMemsetAsync(d_out, 0, (size_t)out_size * sizeof(float), stream);

    dim3 block(256);
    dim3 grid((n + 255) / 256);
    kld_reppoints_kernel<<<grid, block, 0, stream>>>(pred, target, out, n, 1.0f / (float)n);
}